// Round 3
// baseline (163.063 us; speedup 1.0000x reference)
//
#include <hip/hip_runtime.h>

#define NCB 32
#define KK 16
#define DD 128
#define IN_F 4096
#define OUT_F 2048
#define NTOK 2048

// ---------------- K1: lut[c][k][o] = sum_d cent[c][k][d] * W[c][d][o] ----------------
// grid (OUT_F/64, NCB) = (32, 32), block 256. o = tid%64, dgroup = tid/64 (32 d's each).
// cent reads are wave-uniform -> scalar/broadcast cached loads, no LDS stage needed.
__global__ __launch_bounds__(256) void lut_kernel(const float* __restrict__ centroids,
                                                  const float* __restrict__ weight,
                                                  float* __restrict__ lut,
                                                  float* __restrict__ c2out) {
    const int c = blockIdx.y;
    const int o0 = blockIdx.x * 64;
    const int lane_o = threadIdx.x & 63;
    const int dg = threadIdx.x >> 6;
    __shared__ float part[4][KK][64];  // 16 KB

    if (blockIdx.x == 0 && threadIdx.x < KK) {
        const float* cb = centroids + ((size_t)c * KK + threadIdx.x) * DD;
        float s = 0.f;
        for (int d = 0; d < DD; ++d) { float v = cb[d]; s += v * v; }
        c2out[c * KK + threadIdx.x] = s;
    }

    float acc[KK];
#pragma unroll
    for (int k = 0; k < KK; ++k) acc[k] = 0.f;
    const float* wbase = weight + (size_t)c * DD * OUT_F + o0 + lane_o;
    const float* cbase = centroids + (size_t)c * KK * DD;
#pragma unroll
    for (int chunk = 0; chunk < 8; ++chunk) {
        const int d = dg * 32 + chunk * 4;
        float w0 = wbase[(size_t)(d + 0) * OUT_F];
        float w1 = wbase[(size_t)(d + 1) * OUT_F];
        float w2 = wbase[(size_t)(d + 2) * OUT_F];
        float w3 = wbase[(size_t)(d + 3) * OUT_F];
#pragma unroll
        for (int k = 0; k < KK; ++k) {
            float4 cv = *(const float4*)(cbase + k * DD + d);  // wave-uniform addr
            acc[k] += cv.x * w0 + cv.y * w1 + cv.z * w2 + cv.w * w3;
        }
    }
#pragma unroll
    for (int k = 0; k < KK; ++k) part[dg][k][lane_o] = acc[k];
    __syncthreads();
#pragma unroll
    for (int r = 0; r < 4; ++r) {
        int i = r * 256 + threadIdx.x;
        int k = i >> 6, o = i & 63;
        float s = part[0][k][o] + part[1][k][o] + part[2][k][o] + part[3][k][o];
        lut[((size_t)c * KK + k) * OUT_F + o0 + o] = s;
    }
}

// ---------------- K2: idx[t][c] = argmin_k (c2[c][k] - 2*dot(x[t], cent[c][k])) --------
// grid (NTOK/64, NCB) = (32, 32), block 256. Thread = (th_t: 4 tokens, th_k: 4 k, th_q: 32 d).
// cent in LDS with bank-engineered layout: q-stride 40 fl (8-bank shift), k-stride 164 fl
// (4-bank shift) -> worst aliasing 2-way (free). Register-blocked 4x4 -> VALU-bound.
__global__ __launch_bounds__(256) void idx_kernel(const float* __restrict__ x,
                                                  const float* __restrict__ centroids,
                                                  const float* __restrict__ c2,
                                                  unsigned char* __restrict__ idxb) {
    const int c = blockIdx.y;
    const int t0 = blockIdx.x * 64;
    const int tid = threadIdx.x;
    const int th_q = tid & 3;
    const int th_k = (tid >> 2) & 3;
    const int th_t = tid >> 4;

    __shared__ float cent_s[KK * 164];  // 10.25 KB

    for (int p = tid; p < KK * 32; p += 256) {  // 512 float4s
        int k = p >> 5, f4 = p & 31;
        int q = f4 >> 3, jj = f4 & 7;
        *(float4*)(cent_s + k * 164 + q * 40 + jj * 4) =
            *(const float4*)(centroids + ((size_t)c * KK + k) * DD + f4 * 4);
    }
    __syncthreads();

    float c2v[4];
#pragma unroll
    for (int kk = 0; kk < 4; ++kk) c2v[kk] = c2[c * KK + th_k * 4 + kk];

    float acc[4][4];
#pragma unroll
    for (int r = 0; r < 4; ++r)
#pragma unroll
        for (int kk = 0; kk < 4; ++kk) acc[r][kk] = 0.f;

    const float* xb0 = x + (size_t)(t0 + th_t * 4) * IN_F + c * DD + th_q * 32;
#pragma unroll
    for (int chunk = 0; chunk < 8; ++chunk) {
        float4 xa[4];
#pragma unroll
        for (int r = 0; r < 4; ++r)
            xa[r] = *(const float4*)(xb0 + (size_t)r * IN_F + chunk * 4);
        float4 ca[4];
#pragma unroll
        for (int kk = 0; kk < 4; ++kk)
            ca[kk] = *(const float4*)(cent_s + (th_k * 4 + kk) * 164 + th_q * 40 + chunk * 4);
#pragma unroll
        for (int r = 0; r < 4; ++r)
#pragma unroll
            for (int kk = 0; kk < 4; ++kk)
                acc[r][kk] += xa[r].x * ca[kk].x + xa[r].y * ca[kk].y
                            + xa[r].z * ca[kk].z + xa[r].w * ca[kk].w;
    }

    // butterfly-reduce over th_q (lane bits 0-1): all lanes end with full dot
#pragma unroll
    for (int r = 0; r < 4; ++r)
#pragma unroll
        for (int kk = 0; kk < 4; ++kk) {
            float a = acc[r][kk];
            a += __shfl_xor(a, 1);
            a += __shfl_xor(a, 2);
            acc[r][kk] = a;
        }

#pragma unroll
    for (int r = 0; r < 4; ++r) {
        float best = c2v[0] - 2.f * acc[r][0];
        int bi = th_k * 4;
#pragma unroll
        for (int kk = 1; kk < 4; ++kk) {
            float v = c2v[kk] - 2.f * acc[r][kk];
            if (v < best) { best = v; bi = th_k * 4 + kk; }
        }
        // combine across th_k (lane bits 2-3), first-index tie-break
#pragma unroll
        for (int s = 4; s <= 8; s <<= 1) {
            float ov = __shfl_xor(best, s);
            int oi = __shfl_xor(bi, s);
            if (ov < best || (ov == best && oi < bi)) { best = ov; bi = oi; }
        }
        if ((tid & 15) == 0)
            idxb[(size_t)(t0 + th_t * 4 + r) * NCB + c] = (unsigned char)bi;
    }
}

// ---------------- K3: out[t][o] = bias[o] + sum_c lut[c][idx[t][c]][o] ------------------
// grid (NTOK/256, OUT_F/32) = (8, 64) = 512 blocks = exactly 2/CU (80 KB LDS each).
// slut rows padded to 36 floats: 16B-aligned, 4-bank shift per row breaks group aliasing.
__global__ __launch_bounds__(256) void gather_kernel(const float* __restrict__ lut,
                                                     const unsigned char* __restrict__ idxb,
                                                     const float* __restrict__ bias,
                                                     float* __restrict__ out) {
    const int t0 = blockIdx.x * 256;
    const int o0 = blockIdx.y * 32;
    __shared__ float slut[NCB * KK * 36];       // 72 KB
    __shared__ unsigned char sidx[256 * NCB];   // 8 KB

    {
        const int row = threadIdx.x >> 3;
        const int q = threadIdx.x & 7;
        for (int r = row; r < NCB * KK; r += 32)
            *(float4*)(slut + r * 36 + q * 4) =
                *(const float4*)(lut + (size_t)r * OUT_F + o0 + q * 4);
    }
    {
        const int4* ig = (const int4*)(idxb + (size_t)t0 * NCB);
        int4* is4 = (int4*)sidx;
        for (int i = threadIdx.x; i < 512; i += 256) is4[i] = ig[i];
    }
    __syncthreads();

    const int oo = (threadIdx.x & 15) * 2;
    const int tl = threadIdx.x >> 4;
    const float2 bv = *(const float2*)(bias + o0 + oo);

    for (int tt = tl; tt < 256; tt += 16) {
        float2 acc = bv;
        const unsigned int* ip = (const unsigned int*)(sidx + tt * NCB);
#pragma unroll
        for (int c4 = 0; c4 < NCB / 4; ++c4) {
            unsigned int iv4 = ip[c4];
#pragma unroll
            for (int b = 0; b < 4; ++b) {
                int cc = c4 * 4 + b;
                int iv = (iv4 >> (8 * b)) & 0xff;
                const float2 v = *(const float2*)(slut + (cc * KK + iv) * 36 + oo);
                acc.x += v.x;
                acc.y += v.y;
            }
        }
        *(float2*)(out + (size_t)(t0 + tt) * OUT_F + o0 + oo) = acc;
    }
}

extern "C" void kernel_launch(void* const* d_in, const int* in_sizes, int n_in,
                              void* d_out, int out_size, void* d_ws, size_t ws_size,
                              hipStream_t stream) {
    const float* x         = (const float*)d_in[0];  // [2,1024,4096]
    const float* centroids = (const float*)d_in[1];  // [32,16,128]
    const float* weight    = (const float*)d_in[2];  // [32,128,2048]
    const float* bias      = (const float*)d_in[4];  // [2048]
    float* out = (float*)d_out;                      // [2048,2048] fp32

    float* lut = (float*)d_ws;                                        // 4 MB
    unsigned char* idxb = (unsigned char*)d_ws + (4u << 20);          // 64 KB
    float* c2 = (float*)((char*)d_ws + (4u << 20) + (64u << 10));     // 2 KB

    lut_kernel<<<dim3(OUT_F / 64, NCB), 256, 0, stream>>>(centroids, weight, lut, c2);
    idx_kernel<<<dim3(NTOK / 64, NCB), 256, 0, stream>>>(x, centroids, c2, idxb);
    gather_kernel<<<dim3(NTOK / 256, OUT_F / 32), 256, 0, stream>>>(lut, idxb, bias, out);
}

// Round 4
// 160.332 us; speedup vs baseline: 1.0170x; 1.0170x over previous
//
#include <hip/hip_runtime.h>

#define NCB 32
#define KK 16
#define DD 128
#define IN_F 4096
#define OUT_F 2048
#define NTOK 2048
#define LUT_BLOCKS ((OUT_F / 64) * NCB)  // 1024
#define IDX_BLOCKS ((NTOK / 64) * NCB)   // 1024

// ---- Launch A: grid-partitioned fusion of lut-build and idx-argmin (independent) ----
// blocks [0,1024): lut[c][k][o] = sum_d cent[c][k][d]*W[c][d][o]   (o-tile 64, 4 d-groups)
// blocks [1024,2048): idx[t][c] = argmin_k (|cent[c][k]|^2 - 2 x[t].cent[c][k])
//   c2 folded into the dot loop (sq of staged centroids) -> no dependency on lut part.
__global__ __launch_bounds__(256) void fused_lut_idx(
    const float* __restrict__ centroids, const float* __restrict__ weight,
    const float* __restrict__ x, float* __restrict__ lut,
    unsigned char* __restrict__ idxb) {
    extern __shared__ float smem[];
    const int tid = threadIdx.x;

    if (blockIdx.x < LUT_BLOCKS) {
        const int c = blockIdx.x >> 5;
        const int o0 = (blockIdx.x & 31) * 64;
        const int lane_o = tid & 63;
        const int dg = tid >> 6;  // 4 d-groups of 32 d each
        float acc[KK];
#pragma unroll
        for (int k = 0; k < KK; ++k) acc[k] = 0.f;
        const float* wbase = weight + (size_t)c * DD * OUT_F + o0 + lane_o;
        const float* cbase = centroids + (size_t)c * KK * DD;
#pragma unroll
        for (int chunk = 0; chunk < 8; ++chunk) {
            const int d = dg * 32 + chunk * 4;
            float w0 = wbase[(size_t)(d + 0) * OUT_F];
            float w1 = wbase[(size_t)(d + 1) * OUT_F];
            float w2 = wbase[(size_t)(d + 2) * OUT_F];
            float w3 = wbase[(size_t)(d + 3) * OUT_F];
#pragma unroll
            for (int k = 0; k < KK; ++k) {
                float4 cv = *(const float4*)(cbase + k * DD + d);  // wave-uniform
                acc[k] += cv.x * w0 + cv.y * w1 + cv.z * w2 + cv.w * w3;
            }
        }
        float* part = smem;  // [4][KK][64] = 16 KB
#pragma unroll
        for (int k = 0; k < KK; ++k) part[(dg * KK + k) * 64 + lane_o] = acc[k];
        __syncthreads();
#pragma unroll
        for (int r = 0; r < 4; ++r) {
            int i = r * 256 + tid;
            int k = i >> 6, o = i & 63;
            float s = part[(0 * KK + k) * 64 + o] + part[(1 * KK + k) * 64 + o]
                    + part[(2 * KK + k) * 64 + o] + part[(3 * KK + k) * 64 + o];
            lut[((size_t)c * KK + k) * OUT_F + o0 + o] = s;
        }
    } else {
        const int bid = blockIdx.x - LUT_BLOCKS;
        const int c = bid & (NCB - 1);
        const int t0 = (bid >> 5) * 64;
        float* cent_s = smem;  // KK*164 floats, bank-engineered (q-stride 40, k-stride 164)
        const int th_q = tid & 3;
        const int th_k = (tid >> 2) & 3;
        const int th_t = tid >> 4;

        for (int p = tid; p < KK * 32; p += 256) {
            int k = p >> 5, f4 = p & 31;
            int q = f4 >> 3, jj = f4 & 7;
            *(float4*)(cent_s + k * 164 + q * 40 + jj * 4) =
                *(const float4*)(centroids + ((size_t)c * KK + k) * DD + f4 * 4);
        }
        __syncthreads();

        float acc[4][4], sq[4];
#pragma unroll
        for (int r = 0; r < 4; ++r)
#pragma unroll
            for (int kk = 0; kk < 4; ++kk) acc[r][kk] = 0.f;
#pragma unroll
        for (int kk = 0; kk < 4; ++kk) sq[kk] = 0.f;

        const float* xb0 = x + (size_t)(t0 + th_t * 4) * IN_F + c * DD + th_q * 32;
#pragma unroll
        for (int chunk = 0; chunk < 8; ++chunk) {
            float4 xa[4];
#pragma unroll
            for (int r = 0; r < 4; ++r)
                xa[r] = *(const float4*)(xb0 + (size_t)r * IN_F + chunk * 4);
            float4 ca[4];
#pragma unroll
            for (int kk = 0; kk < 4; ++kk)
                ca[kk] = *(const float4*)(cent_s + (th_k * 4 + kk) * 164 + th_q * 40 + chunk * 4);
#pragma unroll
            for (int kk = 0; kk < 4; ++kk)
                sq[kk] += ca[kk].x * ca[kk].x + ca[kk].y * ca[kk].y
                        + ca[kk].z * ca[kk].z + ca[kk].w * ca[kk].w;
#pragma unroll
            for (int r = 0; r < 4; ++r)
#pragma unroll
                for (int kk = 0; kk < 4; ++kk)
                    acc[r][kk] += xa[r].x * ca[kk].x + xa[r].y * ca[kk].y
                                + xa[r].z * ca[kk].z + xa[r].w * ca[kk].w;
        }
        // reduce partial d-sums over th_q (lane bits 0-1)
#pragma unroll
        for (int kk = 0; kk < 4; ++kk) {
            float a = sq[kk];
            a += __shfl_xor(a, 1);
            a += __shfl_xor(a, 2);
            sq[kk] = a;
        }
#pragma unroll
        for (int r = 0; r < 4; ++r)
#pragma unroll
            for (int kk = 0; kk < 4; ++kk) {
                float a = acc[r][kk];
                a += __shfl_xor(a, 1);
                a += __shfl_xor(a, 2);
                acc[r][kk] = a;
            }
#pragma unroll
        for (int r = 0; r < 4; ++r) {
            float best = sq[0] - 2.f * acc[r][0];
            int bi = th_k * 4;
#pragma unroll
            for (int kk = 1; kk < 4; ++kk) {
                float v = sq[kk] - 2.f * acc[r][kk];
                if (v < best) { best = v; bi = th_k * 4 + kk; }
            }
            // combine across th_k (lane bits 2-3), first-index tie-break
#pragma unroll
            for (int s = 4; s <= 8; s <<= 1) {
                float ov = __shfl_xor(best, s);
                int oi = __shfl_xor(bi, s);
                if (ov < best || (ov == best && oi < bi)) { best = ov; bi = oi; }
            }
            if ((tid & 15) == 0)
                idxb[(size_t)(t0 + th_t * 4 + r) * NCB + c] = (unsigned char)bi;
        }
    }
}

// ---- Launch B: out[t][o] = bias[o] + sum_c lut[c][idx[t][c]][o] ----
// grid (NTOK/256, OUT_F/32) = 512 blocks = 2/CU (80 KB LDS). Rows padded to 36 floats.
__global__ __launch_bounds__(256) void gather_kernel(const float* __restrict__ lut,
                                                     const unsigned char* __restrict__ idxb,
                                                     const float* __restrict__ bias,
                                                     float* __restrict__ out) {
    const int t0 = blockIdx.x * 256;
    const int o0 = blockIdx.y * 32;
    __shared__ float slut[NCB * KK * 36];      // 72 KB
    __shared__ unsigned char sidx[256 * NCB];  // 8 KB

    {
        const int row = threadIdx.x >> 3;
        const int q = threadIdx.x & 7;
        for (int r = row; r < NCB * KK; r += 32)
            *(float4*)(slut + r * 36 + q * 4) =
                *(const float4*)(lut + (size_t)r * OUT_F + o0 + q * 4);
    }
    {
        const int4* ig = (const int4*)(idxb + (size_t)t0 * NCB);
        int4* is4 = (int4*)sidx;
        for (int i = threadIdx.x; i < 512; i += 256) is4[i] = ig[i];
    }
    __syncthreads();

    const int oo = (threadIdx.x & 15) * 2;
    const int tl = threadIdx.x >> 4;
    const float2 bv = *(const float2*)(bias + o0 + oo);

    for (int tt = tl; tt < 256; tt += 16) {
        float2 acc = bv;
        const unsigned int* ip = (const unsigned int*)(sidx + tt * NCB);
#pragma unroll
        for (int c4 = 0; c4 < NCB / 4; ++c4) {
            unsigned int iv4 = ip[c4];  // 4 packed indices, wave-broadcast
#pragma unroll
            for (int b = 0; b < 4; ++b) {
                int cc = c4 * 4 + b;
                int iv = (iv4 >> (8 * b)) & 0xff;
                const float2 v = *(const float2*)(slut + (cc * KK + iv) * 36 + oo);
                acc.x += v.x;
                acc.y += v.y;
            }
        }
        *(float2*)(out + (size_t)(t0 + tt) * OUT_F + o0 + oo) = acc;
    }
}

extern "C" void kernel_launch(void* const* d_in, const int* in_sizes, int n_in,
                              void* d_out, int out_size, void* d_ws, size_t ws_size,
                              hipStream_t stream) {
    const float* x         = (const float*)d_in[0];  // [2,1024,4096]
    const float* centroids = (const float*)d_in[1];  // [32,16,128]
    const float* weight    = (const float*)d_in[2];  // [32,128,2048]
    const float* bias      = (const float*)d_in[4];  // [2048]
    float* out = (float*)d_out;                      // [2048,2048] fp32

    float* lut = (float*)d_ws;                               // 4 MB
    unsigned char* idxb = (unsigned char*)d_ws + (4u << 20); // 64 KB

    fused_lut_idx<<<LUT_BLOCKS + IDX_BLOCKS, 256, 16384, stream>>>(
        centroids, weight, x, lut, idxb);
    gather_kernel<<<dim3(NTOK / 256, OUT_F / 32), 256, 0, stream>>>(lut, idxb, bias, out);
}